// Round 2
// baseline (1310.851 us; speedup 1.0000x reference)
//
#include <hip/hip_runtime.h>

typedef unsigned int uint;

#define N_NODES 1024
#define F_DIM   128
#define ROW_ELems 260u
#define ADJ_ELEMS 272629760ull   // 1024*1024*260
#define NN 1048576u              // 1024*1024

// Kernel 1: row norms of z (fp32), one wave per row. 1024 rows, 4 waves/block.
__global__ void norms_kernel(const float* __restrict__ z, float* __restrict__ norms) {
    const uint wave = blockIdx.x * 4u + (threadIdx.x >> 6);
    const uint lane = threadIdx.x & 63u;
    // row has 128 fp32 = 64 float2; each lane loads one float2
    const float2* zr = (const float2*)(z + (size_t)wave * F_DIM);
    float2 p = zr[lane];
    float s = p.x * p.x + p.y * p.y;
    s += __shfl_xor(s, 1, 64);
    s += __shfl_xor(s, 2, 64);
    s += __shfl_xor(s, 4, 64);
    s += __shfl_xor(s, 8, 64);
    s += __shfl_xor(s, 16, 64);
    s += __shfl_xor(s, 32, 64);
    if (lane == 0) norms[wave] = sqrtf(s);
}

// Kernel 2: one wave per output row (i,j).
//   row = 260 fp32 = 1040 B = 65 x float4 chunks
//   lanes 0..31  hold z_i chunk (float4), lanes 32..63 hold z_j chunk
//   every lane stores its 16B chunk (coalesced 1024B/wave)
//   lane 63 also gathers the 4 raw_adj values (chunk 64)
//   fused cosine: shfl_xor(32) swap + 4-elem partial dot + butterfly reduce
__global__ void __launch_bounds__(256) adj_cos_kernel(
        const float* __restrict__ z,
        const float* __restrict__ radj,
        const float* __restrict__ norms,
        float* __restrict__ adj_out,
        float* __restrict__ cos_out) {
    const uint wave = blockIdx.x * 4u + (threadIdx.x >> 6);
    const uint lane = threadIdx.x & 63u;
    const uint i = wave >> 10;
    const uint j = wave & 1023u;

    const float4* zz = (const float4*)z;         // 32 float4 per row
    const uint src = (lane < 32u) ? (i * 32u + lane) : (j * 32u + (lane - 32u));
    const float4 v = zz[src];

    float* row_out = adj_out + (size_t)wave * 260u;
    *(float4*)(row_out + lane * 4u) = v;         // byte offset lane*16, 16B aligned

    if (lane == 63u) {
        const size_t base = (size_t)i * N_NODES + j;
        float4 t;
        t.x = radj[base];
        t.y = radj[base + (size_t)NN];
        t.z = radj[base + 2ull * NN];
        t.w = radj[base + 3ull * NN];
        *(float4*)(row_out + 256u) = t;          // byte offset 1024, 16B aligned
    }

    // fused cosine similarity: lanes<32 hold z_i, lanes>=32 hold z_j; swap halves
    float b0 = __shfl_xor(v.x, 32, 64);
    float b1 = __shfl_xor(v.y, 32, 64);
    float b2 = __shfl_xor(v.z, 32, 64);
    float b3 = __shfl_xor(v.w, 32, 64);
    float p = v.x * b0 + v.y * b1 + v.z * b2 + v.w * b3;
    p += __shfl_xor(p, 1, 64);
    p += __shfl_xor(p, 2, 64);
    p += __shfl_xor(p, 4, 64);
    p += __shfl_xor(p, 8, 64);
    p += __shfl_xor(p, 16, 64);
    if (lane == 0u) {
        float denom = fmaxf(norms[i] * norms[j], 1e-6f);
        cos_out[wave] = p / denom;
    }
}

extern "C" void kernel_launch(void* const* d_in, const int* in_sizes, int n_in,
                              void* d_out, int out_size, void* d_ws, size_t ws_size,
                              hipStream_t stream) {
    const float* z    = (const float*)d_in[0];   // [1024,128] fp32
    const float* radj = (const float*)d_in[1];   // [4,1024,1024] fp32
    float* out   = (float*)d_out;
    float* norms = (float*)d_ws;                 // 1024 floats scratch

    norms_kernel<<<N_NODES / 4, 256, 0, stream>>>(z, norms);

    // 1M waves = 1M output rows; 4 waves/block -> 262144 blocks
    adj_cos_kernel<<<NN / 4, 256, 0, stream>>>(
        z, radj, norms, out, out + ADJ_ELEMS);
}